// Round 3
// baseline (437.829 us; speedup 1.0000x reference)
//
#include <hip/hip_runtime.h>

#define B_    64
#define C_    2048
#define HW_   288
#define EPS_  0.07f
#define TINY_ 1e-8f
#define NCH_  64
#define CPC_  (C_ / NCH_)   // 32 rows per chunk
#define NGRP_ 16            // chunk-groups per batch (4 chunks / group = 1 block)

__device__ __forceinline__ float comp(const float4 v, int i) {
  return i == 0 ? v.x : i == 1 ? v.y : i == 2 ? v.z : v.w;
}

__device__ __forceinline__ void acc3(const float4 v, float a0, float a1,
                                     float* ssq, float* sd0, float* sd1) {
  ssq[0] += v.x * v.x; ssq[1] += v.y * v.y; ssq[2] += v.z * v.z; ssq[3] += v.w * v.w;
  sd0[0] += v.x * a0;  sd0[1] += v.y * a0;  sd0[2] += v.z * a0;  sd0[3] += v.w * a0;
  sd1[0] += v.x * a1;  sd1[1] += v.y * a1;  sd1[2] += v.z * a1;  sd1[3] += v.w * a1;
}

// ---------------------------------------------------------------------------
// Kernel 0: zero per-batch arrival counters (ws is poison-filled every
// iteration) and hoist anchor inverse-norms. 1 block, ~1.5 us.
// ---------------------------------------------------------------------------
__global__ __launch_bounds__(256) void k0_init(
    const float* __restrict__ anchors, unsigned* __restrict__ counters,
    float* __restrict__ ian) {
  int t = threadIdx.x, lane = t & 63, wid = t >> 6;
  __shared__ float red0[4], red1[4];
  float a0 = 0.f, a1 = 0.f;
  for (int c = t; c < C_; c += 256) {
    float q0 = anchors[c], q1 = anchors[C_ + c];
    a0 += q0 * q0; a1 += q1 * q1;
  }
#pragma unroll
  for (int off = 32; off >= 1; off >>= 1) {
    a0 += __shfl_down(a0, off);
    a1 += __shfl_down(a1, off);
  }
  if (lane == 0) { red0[wid] = a0; red1[wid] = a1; }
  __syncthreads();
  if (t == 0) {
    float s0 = red0[0] + red0[1] + red0[2] + red0[3];
    float s1 = red1[0] + red1[1] + red1[2] + red1[3];
    ian[0] = 1.0f / fmaxf(sqrtf(s0), 1e-12f);
    ian[1] = 1.0f / fmaxf(sqrtf(s1), 1e-12f);
  }
  if (t < B_) counters[t] = 0u;
}

// ---------------------------------------------------------------------------
// Kernel 1: per-token partial sums (R1-proven core), one C-chunk per WAVE,
// x-rows AND anchors double-buffered in 4-row groups; 4 waves combine their
// chunk partials in LDS and write one group-partial.
// NEW: last-arriving block per batch (atomic counter) runs the ENTIRE
// Sinkhorn for its batch on wave 0 only — 5 tokens/lane, shfl_xor butterfly
// allreduce, zero barriers (~1 us) — and writes m + invden. Replaces the
// serial k2 dispatch; the 64 tails run while peer blocks drain.
// grid = B*NCH/4 = 1024 blocks, 256 threads.
// part layout: [B][NGRP_][3 planes][288] (3.54 MB).
// ---------------------------------------------------------------------------
__global__ __launch_bounds__(256) void k1_partials(
    const float* __restrict__ x, const float* __restrict__ anchors,
    float* __restrict__ part, unsigned* __restrict__ counters,
    const float* __restrict__ ian, float* __restrict__ out_m,
    float* __restrict__ invden) {
  __shared__ float4 lds[4][3][72];   // [wave][plane][float4 token-quad] = 13.8 KB

  int bi = blockIdx.x;
  int b  = bi >> 4;                // NGRP_ = 16 chunk-groups per b
  int cg = bi & 15;
  int t = threadIdx.x, lane = t & 63, wid = t >> 6;
  int ch = cg * 4 + wid;
  int c0 = ch * CPC_;
  const float* xb = x + ((size_t)b * C_ + c0) * HW_;
  const float4* a0v = (const float4*)(anchors + c0);        // c0 % 32 == 0
  const float4* a1v = (const float4*)(anchors + C_ + c0);

  float ssq[4] = {0,0,0,0}, sd0[4] = {0,0,0,0}, sd1[4] = {0,0,0,0};

  float4 xbuf[4], abuf0, abuf1;
#pragma unroll
  for (int j = 0; j < 4; ++j)
    xbuf[j] = ((const float4*)(xb + (size_t)j * HW_))[lane];
  abuf0 = a0v[0];
  abuf1 = a1v[0];

#pragma unroll 1
  for (int r = 0; r < CPC_; r += 4) {
    float4 xcur[4], ac0 = abuf0, ac1 = abuf1;
#pragma unroll
    for (int j = 0; j < 4; ++j) xcur[j] = xbuf[j];
    if (r + 4 < CPC_) {
#pragma unroll
      for (int j = 0; j < 4; ++j)
        xbuf[j] = ((const float4*)(xb + (size_t)(r + 4 + j) * HW_))[lane];
      abuf0 = a0v[(r >> 2) + 1];
      abuf1 = a1v[(r >> 2) + 1];
    }
#pragma unroll
    for (int j = 0; j < 4; ++j)
      acc3(xcur[j], comp(ac0, j), comp(ac1, j), ssq, sd0, sd1);
  }

  // tail: h float4s 64..71 (one 128B line per row); rows k*8+(lane>>3)
  int rg = lane >> 3, q = lane & 7;
  float4 tv[4];
  float ta0[4], ta1[4];
#pragma unroll
  for (int k = 0; k < CPC_ / 8; ++k) {
    int r = k * 8 + rg;
    tv[k]  = ((const float4*)(xb + (size_t)r * HW_))[64 + q];
    ta0[k] = anchors[c0 + r];
    ta1[k] = anchors[C_ + c0 + r];
  }
  float tsq[4] = {0,0,0,0}, td0[4] = {0,0,0,0}, td1[4] = {0,0,0,0};
#pragma unroll
  for (int k = 0; k < CPC_ / 8; ++k)
    acc3(tv[k], ta0[k], ta1[k], tsq, td0, td1);
#pragma unroll
  for (int off = 8; off < 64; off <<= 1) {
#pragma unroll
    for (int j = 0; j < 4; ++j) {
      tsq[j] += __shfl_xor(tsq[j], off);
      td0[j] += __shfl_xor(td0[j], off);
      td1[j] += __shfl_xor(td1[j], off);
    }
  }

  // Stage this wave's 3x288-float chunk partials into LDS.
  lds[wid][0][lane] = make_float4(ssq[0], ssq[1], ssq[2], ssq[3]);
  lds[wid][1][lane] = make_float4(sd0[0], sd0[1], sd0[2], sd0[3]);
  lds[wid][2][lane] = make_float4(sd1[0], sd1[1], sd1[2], sd1[3]);
  if (lane < 8) {
    lds[wid][0][64 + lane] = make_float4(tsq[0], tsq[1], tsq[2], tsq[3]);
    lds[wid][1][64 + lane] = make_float4(td0[0], td0[1], td0[2], td0[3]);
    lds[wid][2][64 + lane] = make_float4(td1[0], td1[1], td1[2], td1[3]);
  }
  __syncthreads();

  // Combine the 4 waves' chunks and write ONE group-partial (3*288 floats).
  if (t < 216) {
    int p = t / 72, i = t - p * 72;
    float4 s0 = lds[0][p][i], s1 = lds[1][p][i];
    float4 s2 = lds[2][p][i], s3 = lds[3][p][i];
    float4 s = make_float4(s0.x + s1.x + s2.x + s3.x,
                           s0.y + s1.y + s2.y + s3.y,
                           s0.z + s1.z + s2.z + s3.z,
                           s0.w + s1.w + s2.w + s3.w);
    ((float4*)(part + ((size_t)(b * NGRP_ + cg) * 3 + p) * HW_))[i] = s;
  }

  // ---- arrival: release our partial, count arrivals for batch b ----
  __threadfence();                       // device-scope release of part writes
  __shared__ unsigned sdone;
  if (t == 0) sdone = atomicAdd(&counters[b], 1u);
  __syncthreads();
  if (sdone != NGRP_ - 1) return;        // not the last arriver
  if (t >= 64) return;                   // sinkhorn on wave 0 only
  __threadfence();                       // acquire: see peers' part writes

  // ---- wave-level Sinkhorn for batch b: lane l owns tokens l+64j ----
  const float* p = part + (size_t)b * NGRP_ * 3 * HW_;
  float ian0 = ian[0], ian1 = ian[1];
  float K0v[5], K1v[5];
#pragma unroll
  for (int j = 0; j < 5; ++j) {
    int tk = lane + 64 * j;
    K0v[j] = 0.f; K1v[j] = 0.f;
    if (tk < HW_) {
      float ssqs = 0.f, d0s = 0.f, d1s = 0.f;
#pragma unroll
      for (int g = 0; g < NGRP_; ++g) {
        const float* qp = p + (size_t)g * 3 * HW_ + tk;
        ssqs += qp[0];
        d0s  += qp[HW_];
        d1s  += qp[2 * HW_];
      }
      float ixn = 1.0f / fmaxf(sqrtf(ssqs), 1e-12f);
      K0v[j] = expf((d0s * ixn * ian0 - 1.0f) / EPS_) + TINY_;
      K1v[j] = expf((d1s * ixn * ian1 - 1.0f) / EPS_) + TINY_;
    }
  }

  float v0 = 1.f, v1 = 1.f, uv[5];
  for (int it = 0; it < 7; ++it) {
    float p0 = 0.f, p1 = 0.f;
#pragma unroll
    for (int j = 0; j < 5; ++j) {
      int tk = lane + 64 * j;
      uv[j] = (tk < HW_)
            ? (1.0f / (float)HW_) / (K0v[j] * v0 + K1v[j] * v1 + TINY_) : 0.f;
      p0 += K0v[j] * uv[j];
      p1 += K1v[j] * uv[j];
    }
#pragma unroll
    for (int off = 1; off < 64; off <<= 1) {
      p0 += __shfl_xor(p0, off);
      p1 += __shfl_xor(p1, off);
    }
    v0 = 0.5f / (p0 + TINY_);
    v1 = 0.5f / (p1 + TINY_);
  }

  float q0 = 0.f, q1 = 0.f;
#pragma unroll
  for (int j = 0; j < 5; ++j) {
    int tk = lane + 64 * j;
    if (tk < HW_) {
      float m0 = K0v[j] * uv[j] * v0 * (float)HW_;
      float m1 = K1v[j] * uv[j] * v1 * (float)HW_;
      out_m[(b * 2 + 0) * HW_ + tk] = m0;
      out_m[(b * 2 + 1) * HW_ + tk] = m1;
      q0 += m0; q1 += m1;
    }
  }
#pragma unroll
  for (int off = 1; off < 64; off <<= 1) {
    q0 += __shfl_xor(q0, off);
    q1 += __shfl_xor(q1, off);
  }
  if (lane == 0) {
    invden[2 * b + 0] = 1.0f / (q0 + 1e-6f);
    invden[2 * b + 1] = 1.0f / (q1 + 1e-6f);
  }
}

// ---------------------------------------------------------------------------
// Kernel 3 (R1-proven, unchanged): masked pooling. TRANSACTION-COALESCED
// octant mapping; mask fragments register-resident across all 128 rows.
// grid = B*16 = 1024 blocks, 256 threads, 4 row-groups each.
// ---------------------------------------------------------------------------
__global__ __launch_bounds__(256) void k3_pool(
    const float* __restrict__ x, const float* __restrict__ m,
    const float* __restrict__ invden, float* __restrict__ out) {
  int bi = blockIdx.x;
  int b = bi >> 4, seg = bi & 15;
  int t = threadIdx.x, oct = t & 7, rl = t >> 3;   // rl = 0..31

  const float4* m0 = (const float4*)(m + (b * 2 + 0) * HW_);
  const float4* m1 = (const float4*)(m + (b * 2 + 1) * HW_);
  float4 w0[9], w1[9];
#pragma unroll
  for (int j = 0; j < 9; ++j) {
    w0[j] = m0[oct + 8 * j];
    w1[j] = m1[oct + 8 * j];
  }
  float inv0 = invden[2 * b], inv1 = invden[2 * b + 1];

  int cbase = seg * 128;
#pragma unroll 1
  for (int g = 0; g < 4; ++g) {
    int c = cbase + g * 32 + rl;
    const float4* xr = (const float4*)(x + ((size_t)b * C_ + c) * HW_);
    float4 xa[9];
#pragma unroll
    for (int j = 0; j < 9; ++j) xa[j] = xr[oct + 8 * j];
    float a0 = 0.f, a1 = 0.f;
#pragma unroll
    for (int j = 0; j < 9; ++j) {
      a0 += xa[j].x * w0[j].x + xa[j].y * w0[j].y + xa[j].z * w0[j].z + xa[j].w * w0[j].w;
      a1 += xa[j].x * w1[j].x + xa[j].y * w1[j].y + xa[j].z * w1[j].z + xa[j].w * w1[j].w;
    }
#pragma unroll
    for (int off = 4; off >= 1; off >>= 1) {
      a0 += __shfl_xor(a0, off);
      a1 += __shfl_xor(a1, off);
    }
    if (oct == 0) {
      out[(size_t)b * C_ + c] = a0 * inv0;
      out[(size_t)B_ * C_ + (size_t)b * C_ + c] = a1 * inv1;
    }
  }
}

extern "C" void kernel_launch(void* const* d_in, const int* in_sizes, int n_in,
                              void* d_out, int out_size, void* d_ws, size_t ws_size,
                              hipStream_t stream) {
  const float* x       = (const float*)d_in[0];
  const float* anchors = (const float*)d_in[1];
  float* out = (float*)d_out;

  // ws layout: counters[64 u32] | ian[2] | pad | invden[128] | pad | part
  unsigned* counters = (unsigned*)d_ws;            // 64 u32  @ float idx 0..63
  float* ian    = (float*)d_ws + 64;               // 2 floats
  float* invden = (float*)d_ws + 72;               // 128 floats
  float* part   = (float*)d_ws + 208;              // 832 B offset, 16B-aligned

  float* out_m = out + 2 * B_ * C_;  // m region of d_out (B,2,H,W)

  k0_init<<<1, 256, 0, stream>>>(anchors, counters, ian);
  k1_partials<<<B_ * (NCH_ / 4), 256, 0, stream>>>(x, anchors, part, counters,
                                                   ian, out_m, invden);
  k3_pool<<<B_ * 16, 256, 0, stream>>>(x, out_m, invden, out);
}

// Round 4
// 255.978 us; speedup vs baseline: 1.7104x; 1.7104x over previous
//
#include <hip/hip_runtime.h>

#define B_    64
#define C_    2048
#define HW_   288
#define EPS_  0.07f
#define TINY_ 1e-8f
#define NCH_  64
#define CPC_  (C_ / NCH_)   // 32 rows per chunk
#define NGRP_ 16            // chunk-groups per batch (4 chunks / group = 1 block)

__device__ __forceinline__ float comp(const float4 v, int i) {
  return i == 0 ? v.x : i == 1 ? v.y : i == 2 ? v.z : v.w;
}

__device__ __forceinline__ void acc3(const float4 v, float a0, float a1,
                                     float* ssq, float* sd0, float* sd1) {
  ssq[0] += v.x * v.x; ssq[1] += v.y * v.y; ssq[2] += v.z * v.z; ssq[3] += v.w * v.w;
  sd0[0] += v.x * a0;  sd0[1] += v.y * a0;  sd0[2] += v.z * a0;  sd0[3] += v.w * a0;
  sd1[0] += v.x * a1;  sd1[1] += v.y * a1;  sd1[2] += v.z * a1;  sd1[3] += v.w * a1;
}

// ---------------------------------------------------------------------------
// Kernel 1 (R1-proven, unchanged): per-token partial sums, one C-chunk per
// WAVE, x-rows AND anchors double-buffered in 4-row groups; 4 waves combine
// their chunk partials in LDS and write one group-partial.
// grid = B*NCH/4 = 1024 blocks, 256 threads.
// part layout: [B][NGRP_][3 planes][288] (3.54 MB).
// NO fences/atomics — R3 showed per-block device fences cause an L2
// flush/invalidate storm (k1 27us -> 269us). Kernel boundary = coherence.
// ---------------------------------------------------------------------------
__global__ __launch_bounds__(256) void k1_partials(
    const float* __restrict__ x, const float* __restrict__ anchors,
    float* __restrict__ part) {
  __shared__ float4 lds[4][3][72];   // [wave][plane][float4 token-quad] = 13.8 KB

  int bi = blockIdx.x;
  int b  = bi >> 4;                // NGRP_ = 16 chunk-groups per b
  int cg = bi & 15;
  int t = threadIdx.x, lane = t & 63, wid = t >> 6;
  int ch = cg * 4 + wid;
  int c0 = ch * CPC_;
  const float* xb = x + ((size_t)b * C_ + c0) * HW_;
  const float4* a0v = (const float4*)(anchors + c0);        // c0 % 32 == 0
  const float4* a1v = (const float4*)(anchors + C_ + c0);

  float ssq[4] = {0,0,0,0}, sd0[4] = {0,0,0,0}, sd1[4] = {0,0,0,0};

  float4 xbuf[4], abuf0, abuf1;
#pragma unroll
  for (int j = 0; j < 4; ++j)
    xbuf[j] = ((const float4*)(xb + (size_t)j * HW_))[lane];
  abuf0 = a0v[0];
  abuf1 = a1v[0];

#pragma unroll 1
  for (int r = 0; r < CPC_; r += 4) {
    float4 xcur[4], ac0 = abuf0, ac1 = abuf1;
#pragma unroll
    for (int j = 0; j < 4; ++j) xcur[j] = xbuf[j];
    if (r + 4 < CPC_) {
#pragma unroll
      for (int j = 0; j < 4; ++j)
        xbuf[j] = ((const float4*)(xb + (size_t)(r + 4 + j) * HW_))[lane];
      abuf0 = a0v[(r >> 2) + 1];
      abuf1 = a1v[(r >> 2) + 1];
    }
#pragma unroll
    for (int j = 0; j < 4; ++j)
      acc3(xcur[j], comp(ac0, j), comp(ac1, j), ssq, sd0, sd1);
  }

  // tail: h float4s 64..71 (one 128B line per row); rows k*8+(lane>>3)
  int rg = lane >> 3, q = lane & 7;
  float4 tv[4];
  float ta0[4], ta1[4];
#pragma unroll
  for (int k = 0; k < CPC_ / 8; ++k) {
    int r = k * 8 + rg;
    tv[k]  = ((const float4*)(xb + (size_t)r * HW_))[64 + q];
    ta0[k] = anchors[c0 + r];
    ta1[k] = anchors[C_ + c0 + r];
  }
  float tsq[4] = {0,0,0,0}, td0[4] = {0,0,0,0}, td1[4] = {0,0,0,0};
#pragma unroll
  for (int k = 0; k < CPC_ / 8; ++k)
    acc3(tv[k], ta0[k], ta1[k], tsq, td0, td1);
#pragma unroll
  for (int off = 8; off < 64; off <<= 1) {
#pragma unroll
    for (int j = 0; j < 4; ++j) {
      tsq[j] += __shfl_xor(tsq[j], off);
      td0[j] += __shfl_xor(td0[j], off);
      td1[j] += __shfl_xor(td1[j], off);
    }
  }

  // Stage this wave's 3x288-float chunk partials into LDS.
  lds[wid][0][lane] = make_float4(ssq[0], ssq[1], ssq[2], ssq[3]);
  lds[wid][1][lane] = make_float4(sd0[0], sd0[1], sd0[2], sd0[3]);
  lds[wid][2][lane] = make_float4(sd1[0], sd1[1], sd1[2], sd1[3]);
  if (lane < 8) {
    lds[wid][0][64 + lane] = make_float4(tsq[0], tsq[1], tsq[2], tsq[3]);
    lds[wid][1][64 + lane] = make_float4(td0[0], td0[1], td0[2], td0[3]);
    lds[wid][2][64 + lane] = make_float4(td1[0], td1[1], td1[2], td1[3]);
  }
  __syncthreads();

  // Combine the 4 waves' chunks and write ONE group-partial (3*288 floats).
  if (t < 216) {
    int p = t / 72, i = t - p * 72;
    float4 s0 = lds[0][p][i], s1 = lds[1][p][i];
    float4 s2 = lds[2][p][i], s3 = lds[3][p][i];
    float4 s = make_float4(s0.x + s1.x + s2.x + s3.x,
                           s0.y + s1.y + s2.y + s3.y,
                           s0.z + s1.z + s2.z + s3.z,
                           s0.w + s1.w + s2.w + s3.w);
    ((float4*)(part + ((size_t)(b * NGRP_ + cg) * 3 + p) * HW_))[i] = s;
  }
}

// ---------------------------------------------------------------------------
// Kernel 2: BARRIER-FREE wave Sinkhorn (logic verified in R3). One wave per
// batch: lane l owns tokens l+64j (j=0..4); all reductions are shfl_xor
// butterflies — zero __syncthreads, zero LDS. Anchor norms computed per
// block (2048*2 L2-hot floats). grid = 64 blocks, 64 threads.
// ---------------------------------------------------------------------------
__global__ __launch_bounds__(64) void k2_sinkhorn(
    const float* __restrict__ part, const float* __restrict__ anchors,
    float* __restrict__ out_m, float* __restrict__ invden) {
  int b = blockIdx.x, lane = threadIdx.x;

  // ---- collapse group-partials: 5 tokens/lane, coalesced 256B lines ----
  const float* p = part + (size_t)b * NGRP_ * 3 * HW_;
  float ssqv[5], d0v[5], d1v[5];
#pragma unroll
  for (int j = 0; j < 5; ++j) {
    ssqv[j] = 0.f; d0v[j] = 0.f; d1v[j] = 0.f;
    int tk = lane + 64 * j;
    if (tk < HW_) {
#pragma unroll
      for (int g = 0; g < NGRP_; ++g) {
        const float* qp = p + (size_t)g * 3 * HW_ + tk;
        ssqv[j] += qp[0];
        d0v[j]  += qp[HW_];
        d1v[j]  += qp[2 * HW_];
      }
    }
  }

  // ---- anchor inverse-norms (32 elems/lane + butterfly) ----
  float a0 = 0.f, a1 = 0.f;
  for (int c = lane; c < C_; c += 64) {
    float q0 = anchors[c], q1 = anchors[C_ + c];
    a0 += q0 * q0; a1 += q1 * q1;
  }
#pragma unroll
  for (int off = 1; off < 64; off <<= 1) {
    a0 += __shfl_xor(a0, off);
    a1 += __shfl_xor(a1, off);
  }
  float ian0 = 1.0f / fmaxf(sqrtf(a0), 1e-12f);
  float ian1 = 1.0f / fmaxf(sqrtf(a1), 1e-12f);

  // ---- K entries ----
  float K0v[5], K1v[5];
#pragma unroll
  for (int j = 0; j < 5; ++j) {
    int tk = lane + 64 * j;
    K0v[j] = 0.f; K1v[j] = 0.f;
    if (tk < HW_) {
      float ixn = 1.0f / fmaxf(sqrtf(ssqv[j]), 1e-12f);
      K0v[j] = expf((d0v[j] * ixn * ian0 - 1.0f) / EPS_) + TINY_;
      K1v[j] = expf((d1v[j] * ixn * ian1 - 1.0f) / EPS_) + TINY_;
    }
  }

  // ---- 7 Sinkhorn iterations, butterfly allreduce, no barriers ----
  float v0 = 1.f, v1 = 1.f, uv[5];
  for (int it = 0; it < 7; ++it) {
    float p0 = 0.f, p1 = 0.f;
#pragma unroll
    for (int j = 0; j < 5; ++j) {
      int tk = lane + 64 * j;
      uv[j] = (tk < HW_)
            ? (1.0f / (float)HW_) / (K0v[j] * v0 + K1v[j] * v1 + TINY_) : 0.f;
      p0 += K0v[j] * uv[j];
      p1 += K1v[j] * uv[j];
    }
#pragma unroll
    for (int off = 1; off < 64; off <<= 1) {
      p0 += __shfl_xor(p0, off);
      p1 += __shfl_xor(p1, off);
    }
    v0 = 0.5f / (p0 + TINY_);
    v1 = 0.5f / (p1 + TINY_);
  }

  // ---- masks + denominators ----
  float q0 = 0.f, q1 = 0.f;
#pragma unroll
  for (int j = 0; j < 5; ++j) {
    int tk = lane + 64 * j;
    if (tk < HW_) {
      float m0 = K0v[j] * uv[j] * v0 * (float)HW_;
      float m1 = K1v[j] * uv[j] * v1 * (float)HW_;
      out_m[(b * 2 + 0) * HW_ + tk] = m0;
      out_m[(b * 2 + 1) * HW_ + tk] = m1;
      q0 += m0; q1 += m1;
    }
  }
#pragma unroll
  for (int off = 1; off < 64; off <<= 1) {
    q0 += __shfl_xor(q0, off);
    q1 += __shfl_xor(q1, off);
  }
  if (lane == 0) {
    invden[2 * b + 0] = 1.0f / (q0 + 1e-6f);
    invden[2 * b + 1] = 1.0f / (q1 + 1e-6f);
  }
}

// ---------------------------------------------------------------------------
// Kernel 3 (R1-proven, unchanged): masked pooling. TRANSACTION-COALESCED
// octant mapping; mask fragments register-resident across all 128 rows.
// grid = B*16 = 1024 blocks, 256 threads, 4 row-groups each.
// ---------------------------------------------------------------------------
__global__ __launch_bounds__(256) void k3_pool(
    const float* __restrict__ x, const float* __restrict__ m,
    const float* __restrict__ invden, float* __restrict__ out) {
  int bi = blockIdx.x;
  int b = bi >> 4, seg = bi & 15;
  int t = threadIdx.x, oct = t & 7, rl = t >> 3;   // rl = 0..31

  const float4* m0 = (const float4*)(m + (b * 2 + 0) * HW_);
  const float4* m1 = (const float4*)(m + (b * 2 + 1) * HW_);
  float4 w0[9], w1[9];
#pragma unroll
  for (int j = 0; j < 9; ++j) {
    w0[j] = m0[oct + 8 * j];
    w1[j] = m1[oct + 8 * j];
  }
  float inv0 = invden[2 * b], inv1 = invden[2 * b + 1];

  int cbase = seg * 128;
#pragma unroll 1
  for (int g = 0; g < 4; ++g) {
    int c = cbase + g * 32 + rl;
    const float4* xr = (const float4*)(x + ((size_t)b * C_ + c) * HW_);
    float4 xa[9];
#pragma unroll
    for (int j = 0; j < 9; ++j) xa[j] = xr[oct + 8 * j];
    float a0 = 0.f, a1 = 0.f;
#pragma unroll
    for (int j = 0; j < 9; ++j) {
      a0 += xa[j].x * w0[j].x + xa[j].y * w0[j].y + xa[j].z * w0[j].z + xa[j].w * w0[j].w;
      a1 += xa[j].x * w1[j].x + xa[j].y * w1[j].y + xa[j].z * w1[j].z + xa[j].w * w1[j].w;
    }
#pragma unroll
    for (int off = 4; off >= 1; off >>= 1) {
      a0 += __shfl_xor(a0, off);
      a1 += __shfl_xor(a1, off);
    }
    if (oct == 0) {
      out[(size_t)b * C_ + c] = a0 * inv0;
      out[(size_t)B_ * C_ + (size_t)b * C_ + c] = a1 * inv1;
    }
  }
}

extern "C" void kernel_launch(void* const* d_in, const int* in_sizes, int n_in,
                              void* d_out, int out_size, void* d_ws, size_t ws_size,
                              hipStream_t stream) {
  const float* x       = (const float*)d_in[0];
  const float* anchors = (const float*)d_in[1];
  float* out = (float*)d_out;

  // ws layout: invden[128] | part[B*NGRP_*3*288]  (~3.54 MB)
  float* invden = (float*)d_ws;
  float* part = invden + 128;

  float* out_m = out + 2 * B_ * C_;  // m region of d_out (B,2,H,W)

  k1_partials<<<B_ * (NCH_ / 4), 256, 0, stream>>>(x, anchors, part);
  k2_sinkhorn<<<B_, 64, 0, stream>>>(part, anchors, out_m, invden);
  k3_pool<<<B_ * 16, 256, 0, stream>>>(x, out_m, invden, out);
}

// Round 5
// 245.781 us; speedup vs baseline: 1.7814x; 1.0415x over previous
//
#include <hip/hip_runtime.h>

#define B_    64
#define C_    2048
#define HW_   288
#define EPS_  0.07f
#define TINY_ 1e-8f
#define NCH_  64
#define CPC_  (C_ / NCH_)   // 32 rows per chunk
#define NGRP_ 16            // chunk-groups per batch (4 chunks / group = 1 block)

__device__ __forceinline__ float comp(const float4 v, int i) {
  return i == 0 ? v.x : i == 1 ? v.y : i == 2 ? v.z : v.w;
}

__device__ __forceinline__ void acc3(const float4 v, float a0, float a1,
                                     float* ssq, float* sd0, float* sd1) {
  ssq[0] += v.x * v.x; ssq[1] += v.y * v.y; ssq[2] += v.z * v.z; ssq[3] += v.w * v.w;
  sd0[0] += v.x * a0;  sd0[1] += v.y * a0;  sd0[2] += v.z * a0;  sd0[3] += v.w * a0;
  sd1[0] += v.x * a1;  sd1[1] += v.y * a1;  sd1[2] += v.z * a1;  sd1[3] += v.w * a1;
}

// ---------------------------------------------------------------------------
// Kernel 1 (R1-proven, unchanged): per-token partial sums, one C-chunk per
// WAVE, x-rows AND anchors double-buffered in 4-row groups; 4 waves combine
// their chunk partials in LDS and write one group-partial.
// grid = B*NCH/4 = 1024 blocks, 256 threads.
// part layout: [B][NGRP_][3 planes][288] (3.54 MB).
// ---------------------------------------------------------------------------
__global__ __launch_bounds__(256) void k1_partials(
    const float* __restrict__ x, const float* __restrict__ anchors,
    float* __restrict__ part) {
  __shared__ float4 lds[4][3][72];   // [wave][plane][float4 token-quad] = 13.8 KB

  int bi = blockIdx.x;
  int b  = bi >> 4;                // NGRP_ = 16 chunk-groups per b
  int cg = bi & 15;
  int t = threadIdx.x, lane = t & 63, wid = t >> 6;
  int ch = cg * 4 + wid;
  int c0 = ch * CPC_;
  const float* xb = x + ((size_t)b * C_ + c0) * HW_;
  const float4* a0v = (const float4*)(anchors + c0);        // c0 % 32 == 0
  const float4* a1v = (const float4*)(anchors + C_ + c0);

  float ssq[4] = {0,0,0,0}, sd0[4] = {0,0,0,0}, sd1[4] = {0,0,0,0};

  float4 xbuf[4], abuf0, abuf1;
#pragma unroll
  for (int j = 0; j < 4; ++j)
    xbuf[j] = ((const float4*)(xb + (size_t)j * HW_))[lane];
  abuf0 = a0v[0];
  abuf1 = a1v[0];

#pragma unroll 1
  for (int r = 0; r < CPC_; r += 4) {
    float4 xcur[4], ac0 = abuf0, ac1 = abuf1;
#pragma unroll
    for (int j = 0; j < 4; ++j) xcur[j] = xbuf[j];
    if (r + 4 < CPC_) {
#pragma unroll
      for (int j = 0; j < 4; ++j)
        xbuf[j] = ((const float4*)(xb + (size_t)(r + 4 + j) * HW_))[lane];
      abuf0 = a0v[(r >> 2) + 1];
      abuf1 = a1v[(r >> 2) + 1];
    }
#pragma unroll
    for (int j = 0; j < 4; ++j)
      acc3(xcur[j], comp(ac0, j), comp(ac1, j), ssq, sd0, sd1);
  }

  // tail: h float4s 64..71 (one 128B line per row); rows k*8+(lane>>3)
  int rg = lane >> 3, q = lane & 7;
  float4 tv[4];
  float ta0[4], ta1[4];
#pragma unroll
  for (int k = 0; k < CPC_ / 8; ++k) {
    int r = k * 8 + rg;
    tv[k]  = ((const float4*)(xb + (size_t)r * HW_))[64 + q];
    ta0[k] = anchors[c0 + r];
    ta1[k] = anchors[C_ + c0 + r];
  }
  float tsq[4] = {0,0,0,0}, td0[4] = {0,0,0,0}, td1[4] = {0,0,0,0};
#pragma unroll
  for (int k = 0; k < CPC_ / 8; ++k)
    acc3(tv[k], ta0[k], ta1[k], tsq, td0, td1);
#pragma unroll
  for (int off = 8; off < 64; off <<= 1) {
#pragma unroll
    for (int j = 0; j < 4; ++j) {
      tsq[j] += __shfl_xor(tsq[j], off);
      td0[j] += __shfl_xor(td0[j], off);
      td1[j] += __shfl_xor(td1[j], off);
    }
  }

  // Stage this wave's 3x288-float chunk partials into LDS.
  lds[wid][0][lane] = make_float4(ssq[0], ssq[1], ssq[2], ssq[3]);
  lds[wid][1][lane] = make_float4(sd0[0], sd0[1], sd0[2], sd0[3]);
  lds[wid][2][lane] = make_float4(sd1[0], sd1[1], sd1[2], sd1[3]);
  if (lane < 8) {
    lds[wid][0][64 + lane] = make_float4(tsq[0], tsq[1], tsq[2], tsq[3]);
    lds[wid][1][64 + lane] = make_float4(td0[0], td0[1], td0[2], td0[3]);
    lds[wid][2][64 + lane] = make_float4(td1[0], td1[1], td1[2], td1[3]);
  }
  __syncthreads();

  // Combine the 4 waves' chunks and write ONE group-partial (3*288 floats).
  if (t < 216) {
    int p = t / 72, i = t - p * 72;
    float4 s0 = lds[0][p][i], s1 = lds[1][p][i];
    float4 s2 = lds[2][p][i], s3 = lds[3][p][i];
    float4 s = make_float4(s0.x + s1.x + s2.x + s3.x,
                           s0.y + s1.y + s2.y + s3.y,
                           s0.z + s1.z + s2.z + s3.z,
                           s0.w + s1.w + s2.w + s3.w);
    ((float4*)(part + ((size_t)(b * NGRP_ + cg) * 3 + p) * HW_))[i] = s;
  }
}

// Block-wide 2-value sum reduction for 320 threads (5 full waves).
__device__ __forceinline__ void block_reduce2(
    float& p0, float& p1, volatile float* red0, volatile float* red1,
    int t, int nw) {
  int lane = t & 63, wid = t >> 6;
#pragma unroll
  for (int off = 32; off >= 1; off >>= 1) {
    p0 += __shfl_down(p0, off);
    p1 += __shfl_down(p1, off);
  }
  __syncthreads();
  if (lane == 0) { red0[wid] = p0; red1[wid] = p1; }
  __syncthreads();
  float s0 = 0.f, s1 = 0.f;
  for (int w = 0; w < nw; ++w) { s0 += red0[w]; s1 += red1[w]; }
  p0 = s0; p1 = s1;
}

// ---------------------------------------------------------------------------
// Kernel 2 (R1-proven, restored verbatim): group-collapse + per-batch
// Sinkhorn fused. grid = 64 blocks, 320 threads (5 waves — TLP hides the
// collapse-load latency; R4's 1-wave variant was ~10us slower).
// ---------------------------------------------------------------------------
__global__ __launch_bounds__(320) void k2_sinkhorn(
    const float* __restrict__ part, const float* __restrict__ anchors,
    float* __restrict__ out_m, float* __restrict__ invden) {
  int b = blockIdx.x, t = threadIdx.x;
  __shared__ float red0[8], red1[8];
  const int nw = 5;

  float a0 = 0.f, a1 = 0.f;
  for (int c = t; c < C_; c += 320) {
    float q0 = anchors[c], q1 = anchors[C_ + c];
    a0 += q0 * q0; a1 += q1 * q1;
  }
  block_reduce2(a0, a1, red0, red1, t, nw);
  float ian0 = 1.0f / fmaxf(sqrtf(a0), 1e-12f);
  float ian1 = 1.0f / fmaxf(sqrtf(a1), 1e-12f);

  float K0 = 0.f, K1 = 0.f;
  if (t < HW_) {
    const float* p = part + (size_t)b * NGRP_ * 3 * HW_ + t;
    float ssq = 0.f, d0 = 0.f, d1 = 0.f;
#pragma unroll
    for (int g = 0; g < NGRP_; ++g) {
      const float* q = p + (size_t)g * 3 * HW_;
      ssq += q[0];
      d0  += q[HW_];
      d1  += q[2 * HW_];
    }
    float ixn = 1.0f / fmaxf(sqrtf(ssq), 1e-12f);
    K0 = expf((d0 * ixn * ian0 - 1.0f) / EPS_) + TINY_;
    K1 = expf((d1 * ixn * ian1 - 1.0f) / EPS_) + TINY_;
  }

  float v0 = 1.f, v1 = 1.f, u = 0.f;
  for (int it = 0; it < 7; ++it) {
    if (t < HW_) u = (1.0f / (float)HW_) / (K0 * v0 + K1 * v1 + TINY_);
    float p0 = K0 * u, p1 = K1 * u;
    block_reduce2(p0, p1, red0, red1, t, nw);
    v0 = 0.5f / (p0 + TINY_);
    v1 = 0.5f / (p1 + TINY_);
  }

  float m0 = 0.f, m1 = 0.f;
  if (t < HW_) {
    m0 = K0 * u * v0 * (float)HW_;
    m1 = K1 * u * v1 * (float)HW_;
  }
  float q0 = m0, q1 = m1;
  block_reduce2(q0, q1, red0, red1, t, nw);
  if (t < HW_) {
    out_m[(b * 2 + 0) * HW_ + t] = m0;
    out_m[(b * 2 + 1) * HW_ + t] = m1;
  }
  if (t == 0) {
    invden[b * 2 + 0] = 1.0f / (q0 + 1e-6f);
    invden[b * 2 + 1] = 1.0f / (q1 + 1e-6f);
  }
}

// ---------------------------------------------------------------------------
// Kernel 3: masked pooling (R1-proven body). NEW: TEMPORAL-REVERSED,
// XCD-CONGRUENT span mapping. k1 block (b,cg) ran on XCD cg%8 (16b≡0 mod 8);
// its x-span is hottest in that XCD's L2 the LATER it ran. Map dispatch
// index j -> span s with s≡j (mod 8) (same XCD) and s descending in j
// (earliest k3 blocks read k1's last-streamed, still-resident spans).
// Pure index bijection — zero correctness risk.
// grid = B*16 = 1024 blocks, 256 threads, 4 row-groups each.
// ---------------------------------------------------------------------------
__global__ __launch_bounds__(256) void k3_pool(
    const float* __restrict__ x, const float* __restrict__ m,
    const float* __restrict__ invden, float* __restrict__ out) {
  int j = blockIdx.x;
  int s = ((127 - (j >> 3)) << 3) | (j & 7);   // reverse 8-block groups, keep j%8
  int b = s >> 4, seg = s & 15;
  int t = threadIdx.x, oct = t & 7, rl = t >> 3;   // rl = 0..31

  const float4* m0 = (const float4*)(m + (b * 2 + 0) * HW_);
  const float4* m1 = (const float4*)(m + (b * 2 + 1) * HW_);
  float4 w0[9], w1[9];
#pragma unroll
  for (int jj = 0; jj < 9; ++jj) {
    w0[jj] = m0[oct + 8 * jj];
    w1[jj] = m1[oct + 8 * jj];
  }
  float inv0 = invden[2 * b], inv1 = invden[2 * b + 1];

  int cbase = seg * 128;
#pragma unroll 1
  for (int g = 0; g < 4; ++g) {
    int c = cbase + g * 32 + rl;
    const float4* xr = (const float4*)(x + ((size_t)b * C_ + c) * HW_);
    float4 xa[9];
#pragma unroll
    for (int jj = 0; jj < 9; ++jj) xa[jj] = xr[oct + 8 * jj];
    float a0 = 0.f, a1 = 0.f;
#pragma unroll
    for (int jj = 0; jj < 9; ++jj) {
      a0 += xa[jj].x * w0[jj].x + xa[jj].y * w0[jj].y + xa[jj].z * w0[jj].z + xa[jj].w * w0[jj].w;
      a1 += xa[jj].x * w1[jj].x + xa[jj].y * w1[jj].y + xa[jj].z * w1[jj].z + xa[jj].w * w1[jj].w;
    }
#pragma unroll
    for (int off = 4; off >= 1; off >>= 1) {
      a0 += __shfl_xor(a0, off);
      a1 += __shfl_xor(a1, off);
    }
    if (oct == 0) {
      out[(size_t)b * C_ + c] = a0 * inv0;
      out[(size_t)B_ * C_ + (size_t)b * C_ + c] = a1 * inv1;
    }
  }
}

extern "C" void kernel_launch(void* const* d_in, const int* in_sizes, int n_in,
                              void* d_out, int out_size, void* d_ws, size_t ws_size,
                              hipStream_t stream) {
  const float* x       = (const float*)d_in[0];
  const float* anchors = (const float*)d_in[1];
  float* out = (float*)d_out;

  // ws layout: invden[128] | part[B*NGRP_*3*288]  (~3.54 MB)
  float* invden = (float*)d_ws;
  float* part = invden + 128;

  float* out_m = out + 2 * B_ * C_;  // m region of d_out (B,2,H,W)

  k1_partials<<<B_ * (NCH_ / 4), 256, 0, stream>>>(x, anchors, part);
  k2_sinkhorn<<<B_, 320, 0, stream>>>(part, anchors, out_m, invden);
  k3_pool<<<B_ * 16, 256, 0, stream>>>(x, out_m, invden, out);
}